// Round 1
// baseline (936.633 us; speedup 1.0000x reference)
//
#include <hip/hip_runtime.h>
#include <hip/hip_bf16.h>

typedef float f32x4 __attribute__((ext_vector_type(4)));
typedef short s16x8 __attribute__((ext_vector_type(8)));
typedef __hip_bfloat16 bf16;

#define NB 32
#define CB 512
#define DB 2048
#define QB 64
#define HB 16
#define DHB 128

static __device__ __forceinline__ void gload16(const void* g, void* l) {
  __builtin_amdgcn_global_load_lds(
      (const __attribute__((address_space(1))) void*)g,
      (__attribute__((address_space(3))) void*)l, 16, 0, 0);
}

static __device__ __forceinline__ unsigned short f2bf(float f) {
  bf16 b = __float2bfloat16(f);
  return *reinterpret_cast<unsigned short*>(&b);
}

static __device__ __forceinline__ float gelu_f(float z) {
  return 0.5f * z * (1.0f + erff(z * 0.7071067811865475f));
}

// ---------------- convert f32 -> bf16 (n4 = count/4) ----------------
__global__ void k_convert(const float* __restrict__ in, unsigned short* __restrict__ out, int n4) {
  int stride = gridDim.x * blockDim.x;
  for (int i = blockIdx.x * blockDim.x + threadIdx.x; i < n4; i += stride) {
    float4 v = ((const float4*)in)[i];
    ushort4 o;
    o.x = f2bf(v.x); o.y = f2bf(v.y); o.z = f2bf(v.z); o.w = f2bf(v.w);
    ((ushort4*)out)[i] = o;
  }
}

// ---------------- pool: x [N,C,D] -> mean over 8 consecutive c -> xs_bf [N*Q, D] ----------------
__global__ void k_pool(const float* __restrict__ x, bf16* __restrict__ xs) {
  int b = blockIdx.x;                       // N*Q*8 = 16384 blocks
  int d = (b & 7) * 256 + threadIdx.x;
  int q = (b >> 3) & 63;
  int n = b >> 9;
  const float* p = x + ((size_t)(n * CB + q * 8)) * DB + d;
  float s = 0.f;
#pragma unroll
  for (int j = 0; j < 8; ++j) s += p[(size_t)j * DB];
  xs[((size_t)(n * QB + q)) * DB + d] = __float2bfloat16(s * 0.125f);
}

// ---------------- gating: gates[t][e] for 2048 tokens ----------------
__global__ void k_gate(const bf16* __restrict__ xs, const float* __restrict__ wg,
                       float* __restrict__ gates) {
  int t = blockIdx.x * 4 + (threadIdx.x >> 6);
  int lane = threadIdx.x & 63;
  const bf16* row = xs + (size_t)t * DB;
  float z0 = 0.f, z1 = 0.f;
  for (int d = lane; d < DB; d += 64) {
    float v = __bfloat162float(row[d]);
    z0 += v * wg[d * 2];
    z1 += v * wg[d * 2 + 1];
  }
#pragma unroll
  for (int m = 32; m; m >>= 1) { z0 += __shfl_xor(z0, m, 64); z1 += __shfl_xor(z1, m, 64); }
  if (lane == 0) {
    float mx = fmaxf(z0, z1);
    float e0 = __expf(z0 - mx), e1 = __expf(z1 - mx);
    float s = e0 + e1;
    float p0 = e0 / s, p1 = e1 / s;           // softmax (reference does this first)
    float inv = 1.0f / (p0 + p1 + 1e-6f);
    gates[t * 2] = p0 * inv;
    gates[t * 2 + 1] = p1 * inv;
  }
}

// ---------------- transpose + convert: W [2048][2048] f32 -> WT [n][k] bf16 ----------------
__global__ void k_transpose(const float* __restrict__ W, bf16* __restrict__ WT) {
  __shared__ float t[32][33];
  int bx = blockIdx.x * 32;   // col of W (output n)
  int by = blockIdx.y * 32;   // row of W (k)
  int tx = threadIdx.x, ty0 = threadIdx.y;   // block 32 x 8
#pragma unroll
  for (int j = 0; j < 4; ++j) {
    int ty = ty0 + j * 8;
    t[ty][tx] = W[(size_t)(by + ty) * DB + bx + tx];
  }
  __syncthreads();
#pragma unroll
  for (int j = 0; j < 4; ++j) {
    int ty = ty0 + j * 8;
    WT[(size_t)(bx + ty) * DB + by + tx] = __float2bfloat16(t[tx][ty]);
  }
}

// ---------------- GEMM: C[M][2048] = A[M][K] @ BT[2048][K]^T + bias ----------------
// EPI: 0 = bf16 out, 1 = GELU->bf16, 2 = f32 out, 3 = combine (e0*g0 + val*g1 -> f32)
template <int EPI>
__global__ __launch_bounds__(256) void k_gemm(
    const bf16* __restrict__ A, const bf16* __restrict__ BT,
    const float* __restrict__ bias, void* __restrict__ Cout,
    int M, int K,
    const float* __restrict__ e0, const float* __restrict__ gates) {
  constexpr int NN = 2048;
  __shared__ bf16 As[128 * 32];
  __shared__ bf16 Bs[128 * 32];
  const int tid = threadIdx.x;
  const int lane = tid & 63, w = tid >> 6;
  const int m0 = blockIdx.x * 128, n0 = blockIdx.y * 128;
  const int wm = (w >> 1) * 64, wn = (w & 1) * 64;
  f32x4 acc[4][4] = {};

  const int srow = tid >> 2;            // 0..63
  const int scol = (tid & 3) * 8;
  int gr0 = m0 + srow;       if (gr0 > M - 1) gr0 = M - 1;
  int gr1 = m0 + 64 + srow;  if (gr1 > M - 1) gr1 = M - 1;
  const bf16* ag0 = A + (size_t)gr0 * K + scol;
  const bf16* ag1 = A + (size_t)gr1 * K + scol;
  const bf16* bg0 = BT + (size_t)(n0 + srow) * K + scol;
  const bf16* bg1 = BT + (size_t)(n0 + 64 + srow) * K + scol;
  char* lA = (char*)As + w * 1024;
  char* lB = (char*)Bs + w * 1024;

  const int fr = lane & 15, fk = (lane >> 4) * 8;

  for (int k0 = 0; k0 < K; k0 += 32) {
    __syncthreads();
    gload16(ag0 + k0, lA);
    gload16(ag1 + k0, lA + 4096);
    gload16(bg0 + k0, lB);
    gload16(bg1 + k0, lB + 4096);
    __syncthreads();
    s16x8 af[4], bfr[4];
#pragma unroll
    for (int i = 0; i < 4; ++i)
      af[i] = *(const s16x8*)(As + (wm + i * 16 + fr) * 32 + fk);
#pragma unroll
    for (int i = 0; i < 4; ++i)
      bfr[i] = *(const s16x8*)(Bs + (wn + i * 16 + fr) * 32 + fk);
#pragma unroll
    for (int mi = 0; mi < 4; ++mi)
#pragma unroll
      for (int ni = 0; ni < 4; ++ni)
        acc[mi][ni] = __builtin_amdgcn_mfma_f32_16x16x32_bf16(af[mi], bfr[ni], acc[mi][ni], 0, 0, 0);
  }

  const int fg4 = (lane >> 4) * 4;
#pragma unroll
  for (int mi = 0; mi < 4; ++mi) {
#pragma unroll
    for (int ni = 0; ni < 4; ++ni) {
      int col = n0 + wn + ni * 16 + fr;
      float bv = bias[col];
#pragma unroll
      for (int j = 0; j < 4; ++j) {
        int r = m0 + wm + mi * 16 + fg4 + j;
        if (r >= M) continue;
        float v = acc[mi][ni][j] + bv;
        size_t o = (size_t)r * NN + col;
        if (EPI == 0) {
          ((bf16*)Cout)[o] = __float2bfloat16(v);
        } else if (EPI == 1) {
          ((bf16*)Cout)[o] = __float2bfloat16(gelu_f(v));
        } else if (EPI == 2) {
          ((float*)Cout)[o] = v;
        } else {
          float g0 = gates[r * 2], g1 = gates[r * 2 + 1];
          ((float*)Cout)[o] = e0[o] * g0 + v * g1;
        }
      }
    }
  }
}

// ---------------- flash attention per (n,h): Q=64 rows, C=512 keys, DH=128 ----------------
__global__ __launch_bounds__(256) void k_attn(
    const bf16* __restrict__ qg, const bf16* __restrict__ Kg,
    const bf16* __restrict__ Vg, bf16* __restrict__ ctxg) {
  __shared__ bf16 ks[64 * 128];
  __shared__ bf16 vt[128 * 64];
  __shared__ bf16 pb[4][16 * 64];
  const int nh = blockIdx.x;
  const int n = nh >> 4, h = nh & 15;
  const int tid = threadIdx.x, lane = tid & 63, w = tid >> 6;
  const int fr = lane & 15, fg = lane >> 4;

  // Q fragments in registers (wave w handles q rows w*16 .. w*16+15)
  s16x8 aq[4];
  {
    const bf16* qp = qg + (size_t)(w * 16 + fr) * DB + h * DHB + fg * 8;
#pragma unroll
    for (int kk = 0; kk < 4; ++kk) aq[kk] = *(const s16x8*)(qp + kk * 32);
  }
  f32x4 ctx[8] = {};
  float mrow[4], lrow[4];
#pragma unroll
  for (int j = 0; j < 4; ++j) { mrow[j] = -1e30f; lrow[j] = 0.f; }

  const bf16* Kbase = Kg + (size_t)(n * CB) * DB + h * DHB;
  const bf16* Vbase = Vg + (size_t)(n * CB) * DB + h * DHB;
  const float SC = 0.08838834764831845f;   // 1/sqrt(128)

  const int krow = tid >> 4;          // 0..15
  const int kcol = (tid & 15) * 8;

  for (int c0 = 0; c0 < CB; c0 += 64) {
    __syncthreads();
#pragma unroll
    for (int jj = 0; jj < 4; ++jj) {
      int row = jj * 16 + krow;
      *(s16x8*)(ks + row * 128 + kcol) = *(const s16x8*)(Kbase + (size_t)(c0 + row) * DB + kcol);
      s16x8 vv = *(const s16x8*)(Vbase + (size_t)(c0 + row) * DB + kcol);
#pragma unroll
      for (int i = 0; i < 8; ++i)
        vt[(kcol + i) * 64 + row] = ((const bf16*)&vv)[i];
    }
    __syncthreads();

    // S = q @ K^T  (per wave: 16 q rows x 64 c cols)
    f32x4 s4[4] = {};
#pragma unroll
    for (int kk = 0; kk < 4; ++kk) {
#pragma unroll
      for (int ci = 0; ci < 4; ++ci) {
        s16x8 bk = *(const s16x8*)(ks + (ci * 16 + fr) * 128 + kk * 32 + fg * 8);
        s4[ci] = __builtin_amdgcn_mfma_f32_16x16x32_bf16(aq[kk], bk, s4[ci], 0, 0, 0);
      }
    }

    // online softmax on the chunk
#pragma unroll
    for (int j = 0; j < 4; ++j) {
      float m = fmaxf(fmaxf(s4[0][j], s4[1][j]), fmaxf(s4[2][j], s4[3][j])) * SC;
#pragma unroll
      for (int msk = 1; msk < 16; msk <<= 1) m = fmaxf(m, __shfl_xor(m, msk, 16));
      float newm = fmaxf(mrow[j], m);
      float resc = __expf(mrow[j] - newm);
      mrow[j] = newm;
      float rsum = 0.f;
#pragma unroll
      for (int ci = 0; ci < 4; ++ci) {
        float p = __expf(s4[ci][j] * SC - newm);
        rsum += p;
        pb[w][(fg * 4 + j) * 64 + ci * 16 + fr] = __float2bfloat16(p);
      }
#pragma unroll
      for (int msk = 1; msk < 16; msk <<= 1) rsum += __shfl_xor(rsum, msk, 16);
      lrow[j] = lrow[j] * resc + rsum;
#pragma unroll
      for (int ni = 0; ni < 8; ++ni) ctx[ni][j] = ctx[ni][j] * resc;
    }
    __syncthreads();

    // PV: ctx += P @ V
#pragma unroll
    for (int kk2 = 0; kk2 < 2; ++kk2) {
      s16x8 pa = *(const s16x8*)(&pb[w][fr * 64 + kk2 * 32 + fg * 8]);
#pragma unroll
      for (int ni = 0; ni < 8; ++ni) {
        s16x8 bv = *(const s16x8*)(vt + (ni * 16 + fr) * 64 + kk2 * 32 + fg * 8);
        ctx[ni] = __builtin_amdgcn_mfma_f32_16x16x32_bf16(pa, bv, ctx[ni], 0, 0, 0);
      }
    }
  }

#pragma unroll
  for (int ni = 0; ni < 8; ++ni) {
#pragma unroll
    for (int j = 0; j < 4; ++j) {
      int q = w * 16 + fg * 4 + j;
      float v = ctx[ni][j] / lrow[j];
      ctxg[(size_t)(n * QB + q) * DB + h * DHB + ni * 16 + fr] = __float2bfloat16(v);
    }
  }
}

extern "C" void kernel_launch(void* const* d_in, const int* in_sizes, int n_in,
                              void* d_out, int out_size, void* d_ws, size_t ws_size,
                              hipStream_t stream) {
  const float* x  = (const float*)d_in[0];
  const float* w1 = (const float*)d_in[1];
  const float* b1 = (const float*)d_in[2];
  const float* w2 = (const float*)d_in[3];
  const float* b2 = (const float*)d_in[4];
  const float* qt = (const float*)d_in[5];
  const float* wq = (const float*)d_in[6];
  const float* bq = (const float*)d_in[7];
  const float* wk = (const float*)d_in[8];
  const float* bk = (const float*)d_in[9];
  const float* wv = (const float*)d_in[10];
  const float* bv = (const float*)d_in[11];
  const float* wo = (const float*)d_in[12];
  const float* bo = (const float*)d_in[13];
  const float* wg = (const float*)d_in[14];
  float* out = (float*)d_out;

  char* ws = (char*)d_ws;
  size_t off = 0;
  auto alloc = [&](size_t bytes) {
    char* p = ws + off;
    off += (bytes + 255) & ~(size_t)255;
    return p;
  };
  const size_t XE = (size_t)NB * CB * DB;          // 33554432
  const size_t WE = (size_t)DB * DB;               // 4194304
  const size_t TE = (size_t)NB * QB * DB;          // 4194304 tokens*D

  bf16* x_bf   = (bf16*)alloc(XE * 2);
  bf16* K_bf   = (bf16*)alloc(XE * 2);
  bf16* V_bf   = (bf16*)alloc(XE * 2);
  bf16* w1T    = (bf16*)alloc(WE * 2);
  bf16* w2T    = (bf16*)alloc(WE * 2);
  bf16* wkT    = (bf16*)alloc(WE * 2);
  bf16* wvT    = (bf16*)alloc(WE * 2);
  bf16* wqT    = (bf16*)alloc(WE * 2);
  bf16* woT    = (bf16*)alloc(WE * 2);
  bf16* xs_bf  = (bf16*)alloc(TE * 2);
  bf16* h_bf   = (bf16*)alloc(TE * 2);
  bf16* ctx_bf = (bf16*)alloc(TE * 2);
  bf16* res_bf = (bf16*)alloc(TE * 2);
  bf16* qt_bf  = (bf16*)alloc((size_t)QB * DB * 2);
  bf16* q_bf   = (bf16*)alloc((size_t)QB * DB * 2);
  float* e0    = (float*)alloc(TE * 4);
  float* gates = (float*)alloc((size_t)NB * QB * 2 * 4);
  (void)ws_size; (void)in_sizes; (void)n_in; (void)out_size;

  // conversions + pooling + gating
  k_convert<<<2048, 256, 0, stream>>>(x, (unsigned short*)x_bf, (int)(XE / 4));
  k_convert<<<64, 256, 0, stream>>>(qt, (unsigned short*)qt_bf, (int)(QB * DB / 4));
  k_pool<<<NB * QB * 8, 256, 0, stream>>>(x, xs_bf);
  k_gate<<<NB * QB / 4, 256, 0, stream>>>(xs_bf, wg, gates);

  // weight transposes (f32 -> bf16, [k][n] -> [n][k])
  dim3 tb(32, 8), tg(64, 64);
  k_transpose<<<tg, tb, 0, stream>>>(w1, w1T);
  k_transpose<<<tg, tb, 0, stream>>>(w2, w2T);
  k_transpose<<<tg, tb, 0, stream>>>(wk, wkT);
  k_transpose<<<tg, tb, 0, stream>>>(wv, wvT);
  k_transpose<<<tg, tb, 0, stream>>>(wq, wqT);
  k_transpose<<<tg, tb, 0, stream>>>(wo, woT);

  // expert 0 MLP
  k_gemm<1><<<dim3(16, 16), 256, 0, stream>>>(xs_bf, w1T, b1, h_bf, 2048, 2048, nullptr, nullptr);
  k_gemm<2><<<dim3(16, 16), 256, 0, stream>>>(h_bf, w2T, b2, e0, 2048, 2048, nullptr, nullptr);

  // K/V/Q projections
  k_gemm<0><<<dim3(128, 16), 256, 0, stream>>>(x_bf, wkT, bk, K_bf, 16384, 2048, nullptr, nullptr);
  k_gemm<0><<<dim3(128, 16), 256, 0, stream>>>(x_bf, wvT, bv, V_bf, 16384, 2048, nullptr, nullptr);
  k_gemm<0><<<dim3(1, 16), 256, 0, stream>>>(qt_bf, wqT, bq, q_bf, 64, 2048, nullptr, nullptr);

  // cross attention
  k_attn<<<NB * HB, 256, 0, stream>>>(q_bf, K_bf, V_bf, ctx_bf);

  // output proj + expert 1 MLP + gated combine
  k_gemm<0><<<dim3(16, 16), 256, 0, stream>>>(ctx_bf, woT, bo, res_bf, 2048, 2048, nullptr, nullptr);
  k_gemm<1><<<dim3(16, 16), 256, 0, stream>>>(res_bf, w1T, b1, h_bf, 2048, 2048, nullptr, nullptr);
  k_gemm<3><<<dim3(16, 16), 256, 0, stream>>>(h_bf, w2T, b2, out, 2048, 2048, e0, gates);
}

// Round 2
// 787.786 us; speedup vs baseline: 1.1889x; 1.1889x over previous
//
#include <hip/hip_runtime.h>
#include <hip/hip_bf16.h>

typedef float f32x4 __attribute__((ext_vector_type(4)));
typedef short s16x8 __attribute__((ext_vector_type(8)));
typedef __hip_bfloat16 bf16;

#define NB 32
#define CB 512
#define DB 2048
#define QB 64
#define HB 16
#define DHB 128

static __device__ __forceinline__ void gload16(const void* g, void* l) {
  __builtin_amdgcn_global_load_lds(
      (const __attribute__((address_space(1))) void*)g,
      (__attribute__((address_space(3))) void*)l, 16, 0, 0);
}

static __device__ __forceinline__ unsigned short f2bf(float f) {
  bf16 b = __float2bfloat16(f);
  return *reinterpret_cast<unsigned short*>(&b);
}

static __device__ __forceinline__ float gelu_f(float z) {
  return 0.5f * z * (1.0f + erff(z * 0.7071067811865475f));
}

// ---------------- convert f32 -> bf16 (n4 = count/4) ----------------
__global__ void k_convert(const float* __restrict__ in, unsigned short* __restrict__ out, int n4) {
  int stride = gridDim.x * blockDim.x;
  for (int i = blockIdx.x * blockDim.x + threadIdx.x; i < n4; i += stride) {
    float4 v = ((const float4*)in)[i];
    ushort4 o;
    o.x = f2bf(v.x); o.y = f2bf(v.y); o.z = f2bf(v.z); o.w = f2bf(v.w);
    ((ushort4*)out)[i] = o;
  }
}

// ---------------- pool: x [N,C,D] -> mean over 8 consecutive c -> xs_bf [N*Q, D] ----------------
__global__ void k_pool(const float* __restrict__ x, bf16* __restrict__ xs) {
  int b = blockIdx.x;                       // N*Q*8 = 16384 blocks
  int d = (b & 7) * 256 + threadIdx.x;
  int q = (b >> 3) & 63;
  int n = b >> 9;
  const float* p = x + ((size_t)(n * CB + q * 8)) * DB + d;
  float s = 0.f;
#pragma unroll
  for (int j = 0; j < 8; ++j) s += p[(size_t)j * DB];
  xs[((size_t)(n * QB + q)) * DB + d] = __float2bfloat16(s * 0.125f);
}

// ---------------- gating: gates[t][e] for 2048 tokens ----------------
__global__ void k_gate(const bf16* __restrict__ xs, const float* __restrict__ wg,
                       float* __restrict__ gates) {
  int t = blockIdx.x * 4 + (threadIdx.x >> 6);
  int lane = threadIdx.x & 63;
  const bf16* row = xs + (size_t)t * DB;
  float z0 = 0.f, z1 = 0.f;
  for (int d = lane; d < DB; d += 64) {
    float v = __bfloat162float(row[d]);
    z0 += v * wg[d * 2];
    z1 += v * wg[d * 2 + 1];
  }
#pragma unroll
  for (int m = 32; m; m >>= 1) { z0 += __shfl_xor(z0, m, 64); z1 += __shfl_xor(z1, m, 64); }
  if (lane == 0) {
    float mx = fmaxf(z0, z1);
    float e0 = __expf(z0 - mx), e1 = __expf(z1 - mx);
    float s = e0 + e1;
    float p0 = e0 / s, p1 = e1 / s;
    float inv = 1.0f / (p0 + p1 + 1e-6f);
    gates[t * 2] = p0 * inv;
    gates[t * 2 + 1] = p1 * inv;
  }
}

// ---------------- transpose + convert: W [2048][2048] f32 -> WT [n][k] bf16 ----------------
__global__ void k_transpose(const float* __restrict__ W, bf16* __restrict__ WT) {
  __shared__ float t[32][33];
  int bx = blockIdx.x * 32;
  int by = blockIdx.y * 32;
  int tx = threadIdx.x, ty0 = threadIdx.y;
#pragma unroll
  for (int j = 0; j < 4; ++j) {
    int ty = ty0 + j * 8;
    t[ty][tx] = W[(size_t)(by + ty) * DB + bx + tx];
  }
  __syncthreads();
#pragma unroll
  for (int j = 0; j < 4; ++j) {
    int ty = ty0 + j * 8;
    WT[(size_t)(bx + ty) * DB + by + tx] = __float2bfloat16(t[tx][ty]);
  }
}

// ---------------- GEMM: C[M][N] = A[M][K] @ BT[N][K]^T + bias, batched over blockIdx.z ----
// EPI: 0 = bf16 out, 1 = GELU->bf16, 2 = f32 out
template <int EPI>
__global__ __launch_bounds__(256) void k_gemm(
    const bf16* __restrict__ A, int lda, long long sAb,
    const bf16* __restrict__ BT, int ldb, long long sBb,
    const float* __restrict__ bias, void* __restrict__ Cout, int ldc, long long sCb,
    int M, int K) {
  __shared__ bf16 As[128 * 32];
  __shared__ bf16 Bs[128 * 32];
  const int z = blockIdx.z;
  A += (size_t)z * sAb;
  BT += (size_t)z * sBb;
  const int tid = threadIdx.x;
  const int lane = tid & 63, w = tid >> 6;
  const int m0 = blockIdx.x * 128, n0 = blockIdx.y * 128;
  const int wm = (w >> 1) * 64, wn = (w & 1) * 64;
  f32x4 acc[4][4] = {};

  const int srow = tid >> 2;
  const int scol = (tid & 3) * 8;
  int gr0 = m0 + srow;       if (gr0 > M - 1) gr0 = M - 1;
  int gr1 = m0 + 64 + srow;  if (gr1 > M - 1) gr1 = M - 1;
  const bf16* ag0 = A + (size_t)gr0 * lda + scol;
  const bf16* ag1 = A + (size_t)gr1 * lda + scol;
  const bf16* bg0 = BT + (size_t)(n0 + srow) * ldb + scol;
  const bf16* bg1 = BT + (size_t)(n0 + 64 + srow) * ldb + scol;
  char* lA = (char*)As + w * 1024;
  char* lB = (char*)Bs + w * 1024;

  const int fr = lane & 15, fk = (lane >> 4) * 8;

  for (int k0 = 0; k0 < K; k0 += 32) {
    __syncthreads();
    gload16(ag0 + k0, lA);
    gload16(ag1 + k0, lA + 4096);
    gload16(bg0 + k0, lB);
    gload16(bg1 + k0, lB + 4096);
    __syncthreads();
    s16x8 af[4], bfr[4];
#pragma unroll
    for (int i = 0; i < 4; ++i)
      af[i] = *(const s16x8*)(As + (wm + i * 16 + fr) * 32 + fk);
#pragma unroll
    for (int i = 0; i < 4; ++i)
      bfr[i] = *(const s16x8*)(Bs + (wn + i * 16 + fr) * 32 + fk);
#pragma unroll
    for (int mi = 0; mi < 4; ++mi)
#pragma unroll
      for (int ni = 0; ni < 4; ++ni)
        acc[mi][ni] = __builtin_amdgcn_mfma_f32_16x16x32_bf16(af[mi], bfr[ni], acc[mi][ni], 0, 0, 0);
  }

  const int fg4 = (lane >> 4) * 4;
#pragma unroll
  for (int mi = 0; mi < 4; ++mi) {
#pragma unroll
    for (int ni = 0; ni < 4; ++ni) {
      int col = n0 + wn + ni * 16 + fr;
      float bv = bias ? bias[col] : 0.f;
#pragma unroll
      for (int j = 0; j < 4; ++j) {
        int r = m0 + wm + mi * 16 + fg4 + j;
        if (r >= M) continue;
        float v = acc[mi][ni][j] + bv;
        size_t o = (size_t)z * sCb + (size_t)r * ldc + col;
        if (EPI == 0) {
          ((bf16*)Cout)[o] = __float2bfloat16(v);
        } else if (EPI == 1) {
          ((bf16*)Cout)[o] = __float2bfloat16(gelu_f(v));
        } else {
          ((float*)Cout)[o] = v;
        }
      }
    }
  }
}

// ---------------- attention per (n,h): precomputed scores S [N][H*Q][C], V staged, PV ----
__global__ __launch_bounds__(256) void k_attn(
    const bf16* __restrict__ S, const bf16* __restrict__ Vg, bf16* __restrict__ ctxg) {
  __shared__ bf16 vt[128 * 64];
  __shared__ bf16 pb[4][16 * 64];
  const int nh = blockIdx.x;
  const int n = nh >> 4, h = nh & 15;
  const int tid = threadIdx.x, lane = tid & 63, w = tid >> 6;
  const int fr = lane & 15, fg = lane >> 4;

  f32x4 ctx[8] = {};
  float mrow[4], lrow[4];
#pragma unroll
  for (int j = 0; j < 4; ++j) { mrow[j] = -1e30f; lrow[j] = 0.f; }

  const bf16* Srow = S + ((size_t)n * (HB * QB) + h * QB) * CB;  // [64][512]
  const bf16* Vbase = Vg + (size_t)(n * CB) * DB + h * DHB;
  const float SC = 0.08838834764831845f;   // 1/sqrt(128)

  const int krow = tid >> 4;          // 0..15
  const int kcol = (tid & 15) * 8;

  for (int c0 = 0; c0 < CB; c0 += 64) {
    __syncthreads();
#pragma unroll
    for (int jj = 0; jj < 4; ++jj) {
      int row = jj * 16 + krow;
      s16x8 vv = *(const s16x8*)(Vbase + (size_t)(c0 + row) * DB + kcol);
#pragma unroll
      for (int i = 0; i < 8; ++i)
        vt[(kcol + i) * 64 + row] = ((const bf16*)&vv)[i];
    }

    // load scores chunk: s4[ci][j] = S[q = w*16 + fg*4 + j][c0 + ci*16 + fr]
    f32x4 s4[4];
#pragma unroll
    for (int ci = 0; ci < 4; ++ci)
#pragma unroll
      for (int j = 0; j < 4; ++j)
        s4[ci][j] = __bfloat162float(Srow[(size_t)(w * 16 + fg * 4 + j) * CB + c0 + ci * 16 + fr]);

    // online softmax on the chunk
#pragma unroll
    for (int j = 0; j < 4; ++j) {
      float m = fmaxf(fmaxf(s4[0][j], s4[1][j]), fmaxf(s4[2][j], s4[3][j])) * SC;
#pragma unroll
      for (int msk = 1; msk < 16; msk <<= 1) m = fmaxf(m, __shfl_xor(m, msk, 16));
      float newm = fmaxf(mrow[j], m);
      float resc = __expf(mrow[j] - newm);
      mrow[j] = newm;
      float rsum = 0.f;
#pragma unroll
      for (int ci = 0; ci < 4; ++ci) {
        float p = __expf(s4[ci][j] * SC - newm);
        rsum += p;
        pb[w][(fg * 4 + j) * 64 + ci * 16 + fr] = __float2bfloat16(p);
      }
#pragma unroll
      for (int msk = 1; msk < 16; msk <<= 1) rsum += __shfl_xor(rsum, msk, 16);
      lrow[j] = lrow[j] * resc + rsum;
#pragma unroll
      for (int ni = 0; ni < 8; ++ni) ctx[ni][j] = ctx[ni][j] * resc;
    }
    __syncthreads();

    // PV: ctx += P @ V
#pragma unroll
    for (int kk2 = 0; kk2 < 2; ++kk2) {
      s16x8 pa = *(const s16x8*)(&pb[w][fr * 64 + kk2 * 32 + fg * 8]);
#pragma unroll
      for (int ni = 0; ni < 8; ++ni) {
        s16x8 bv = *(const s16x8*)(vt + (ni * 16 + fr) * 64 + kk2 * 32 + fg * 8);
        ctx[ni] = __builtin_amdgcn_mfma_f32_16x16x32_bf16(pa, bv, ctx[ni], 0, 0, 0);
      }
    }
  }

#pragma unroll
  for (int ni = 0; ni < 8; ++ni) {
#pragma unroll
    for (int j = 0; j < 4; ++j) {
      int q = w * 16 + fg * 4 + j;
      float v = ctx[ni][j] / lrow[j];
      ctxg[(size_t)(n * QB + q) * DB + h * DHB + ni * 16 + fr] = __float2bfloat16(v);
    }
  }
}

// ---------------- gated combine: out[t][d] = e01[t][d]*g0[t] + e01[t+2048][d]*g1[t] ----
__global__ void k_combine(const float* __restrict__ e01, const float* __restrict__ gates,
                          float* __restrict__ out) {
  int i = blockIdx.x * blockDim.x + threadIdx.x;   // 1M float4 groups
  int t = i >> 9;                                  // 512 float4 per row
  float4 a = ((const float4*)e01)[i];
  float4 b = ((const float4*)e01)[i + (1 << 20)];  // + 2048*2048/4
  float g0 = gates[t * 2], g1 = gates[t * 2 + 1];
  float4 o;
  o.x = a.x * g0 + b.x * g1;
  o.y = a.y * g0 + b.y * g1;
  o.z = a.z * g0 + b.z * g1;
  o.w = a.w * g0 + b.w * g1;
  ((float4*)out)[i] = o;
}

extern "C" void kernel_launch(void* const* d_in, const int* in_sizes, int n_in,
                              void* d_out, int out_size, void* d_ws, size_t ws_size,
                              hipStream_t stream) {
  const float* x  = (const float*)d_in[0];
  const float* w1 = (const float*)d_in[1];
  const float* b1 = (const float*)d_in[2];
  const float* w2 = (const float*)d_in[3];
  const float* b2 = (const float*)d_in[4];
  const float* qt = (const float*)d_in[5];
  const float* wq = (const float*)d_in[6];
  const float* bq = (const float*)d_in[7];
  const float* wk = (const float*)d_in[8];
  const float* wv = (const float*)d_in[10];
  const float* bv = (const float*)d_in[11];
  const float* wo = (const float*)d_in[12];
  const float* bo = (const float*)d_in[13];
  const float* wg = (const float*)d_in[14];
  float* out = (float*)d_out;

  char* ws = (char*)d_ws;
  size_t off = 0;
  auto alloc = [&](size_t bytes) {
    char* p = ws + off;
    off += (bytes + 255) & ~(size_t)255;
    return p;
  };
  const size_t XE = (size_t)NB * CB * DB;          // 33554432
  const size_t WE = (size_t)DB * DB;               // 4194304
  const size_t TE = (size_t)NB * QB * DB;          // 4194304

  bf16* x_bf   = (bf16*)alloc(XE * 2);
  bf16* V_bf   = (bf16*)alloc(XE * 2);
  bf16* wk_bf  = (bf16*)alloc(WE * 2);             // plain convert, original layout
  bf16* w1T    = (bf16*)alloc(WE * 2);
  bf16* w2T    = (bf16*)alloc(WE * 2);
  bf16* wvT    = (bf16*)alloc(WE * 2);
  bf16* wqT    = (bf16*)alloc(WE * 2);
  bf16* woT    = (bf16*)alloc(WE * 2);
  bf16* tokens = (bf16*)alloc(2 * TE * 2);         // rows 0-2047: xs; rows 2048-4095: res
  bf16* h4     = (bf16*)alloc(2 * TE * 2);
  float* e01   = (float*)alloc(2 * TE * 4);
  bf16* ctx_bf = (bf16*)alloc(TE * 2);
  bf16* qt_bf  = (bf16*)alloc((size_t)QB * DB * 2);
  bf16* qproj  = (bf16*)alloc((size_t)QB * DB * 2);
  bf16* qk     = (bf16*)alloc((size_t)HB * QB * DB * 2);   // [1024][2048]
  bf16* Sbuf   = (bf16*)alloc((size_t)NB * HB * QB * CB * 2); // [32][1024][512]
  float* gates = (float*)alloc((size_t)NB * QB * 2 * 4);
  (void)ws_size; (void)in_sizes; (void)n_in; (void)out_size;

  // conversions + pooling + gating
  k_convert<<<2048, 256, 0, stream>>>(x, (unsigned short*)x_bf, (int)(XE / 4));
  k_convert<<<64, 256, 0, stream>>>(qt, (unsigned short*)qt_bf, (int)(QB * DB / 4));
  k_convert<<<1024, 256, 0, stream>>>(wk, (unsigned short*)wk_bf, (int)(WE / 4));
  k_pool<<<NB * QB * 8, 256, 0, stream>>>(x, tokens);
  k_gate<<<NB * QB / 4, 256, 0, stream>>>(tokens, wg, gates);

  // weight transposes (f32 -> bf16, [k][n] -> [n][k]); wk NOT needed transposed
  dim3 tb(32, 8), tg(64, 64);
  k_transpose<<<tg, tb, 0, stream>>>(w1, w1T);
  k_transpose<<<tg, tb, 0, stream>>>(w2, w2T);
  k_transpose<<<tg, tb, 0, stream>>>(wv, wvT);
  k_transpose<<<tg, tb, 0, stream>>>(wq, wqT);
  k_transpose<<<tg, tb, 0, stream>>>(wo, woT);

  // q projection: qproj[64][2048] = qt @ wq + bq
  k_gemm<0><<<dim3(1, 16, 1), 256, 0, stream>>>(
      qt_bf, DB, 0, wqT, DB, 0, bq, qproj, DB, 0, QB, DB);

  // qk[h][q][d] = sum_dh qproj[q, h*128+dh] * wk[d, h*128+dh]  (batched over h)
  k_gemm<0><<<dim3(1, 16, HB), 256, 0, stream>>>(
      qproj, DB, DHB, wk_bf, DB, DHB, nullptr, qk, DB, (long long)QB * DB, QB, DHB);

  // V projection
  k_gemm<0><<<dim3(128, 16, 1), 256, 0, stream>>>(
      x_bf, DB, 0, wvT, DB, 0, bv, V_bf, DB, 0, NB * CB, DB);

  // scores: S[n][h*64+q][c] = qk @ x[n]^T   (batched over n; bk is softmax-invariant)
  k_gemm<0><<<dim3(8, 4, NB), 256, 0, stream>>>(
      qk, DB, 0, x_bf, DB, (long long)CB * DB, nullptr,
      Sbuf, CB, (long long)HB * QB * CB, HB * QB, DB);

  // cross attention (softmax + PV)
  k_attn<<<NB * HB, 256, 0, stream>>>(Sbuf, V_bf, ctx_bf);

  // output proj -> tokens rows 2048..4095
  k_gemm<0><<<dim3(16, 16, 1), 256, 0, stream>>>(
      ctx_bf, DB, 0, woT, DB, 0, bo, tokens + (size_t)2048 * DB, DB, 0, 2048, DB);

  // stacked expert MLP on [xs; res] (shared weights)
  k_gemm<1><<<dim3(32, 16, 1), 256, 0, stream>>>(
      tokens, DB, 0, w1T, DB, 0, b1, h4, DB, 0, 4096, DB);
  k_gemm<2><<<dim3(32, 16, 1), 256, 0, stream>>>(
      h4, DB, 0, w2T, DB, 0, b2, e01, DB, 0, 4096, DB);

  // gated combine
  k_combine<<<4096, 256, 0, stream>>>(e01, gates, out);
}

// Round 3
// 621.371 us; speedup vs baseline: 1.5074x; 1.2678x over previous
//
#include <hip/hip_runtime.h>
#include <hip/hip_bf16.h>

typedef float f32x4 __attribute__((ext_vector_type(4)));
typedef short s16x8 __attribute__((ext_vector_type(8)));
typedef __hip_bfloat16 bf16;

#define NB 32
#define CB 512
#define DB 2048
#define QB 64
#define HB 16
#define DHB 128

static __device__ __forceinline__ void gload16(const void* g, void* l) {
  __builtin_amdgcn_global_load_lds(
      (const __attribute__((address_space(1))) void*)g,
      (__attribute__((address_space(3))) void*)l, 16, 0, 0);
}

static __device__ __forceinline__ unsigned short f2bf(float f) {
  bf16 b = __float2bfloat16(f);
  return *reinterpret_cast<unsigned short*>(&b);
}

static __device__ __forceinline__ float gelu_f(float z) {
  return 0.5f * z * (1.0f + erff(z * 0.7071067811865475f));
}

#define BAR2 do { asm volatile("" ::: "memory"); __builtin_amdgcn_s_barrier(); asm volatile("" ::: "memory"); } while (0)
#define VM4  asm volatile("s_waitcnt vmcnt(4)" ::: "memory")

// ---------------- convert f32 -> bf16 (n4 = count/4) ----------------
__global__ void k_convert(const float* __restrict__ in, unsigned short* __restrict__ out, int n4) {
  int stride = gridDim.x * blockDim.x;
  for (int i = blockIdx.x * blockDim.x + threadIdx.x; i < n4; i += stride) {
    float4 v = ((const float4*)in)[i];
    ushort4 o;
    o.x = f2bf(v.x); o.y = f2bf(v.y); o.z = f2bf(v.z); o.w = f2bf(v.w);
    ((ushort4*)out)[i] = o;
  }
}

// ---------------- pool: x [N,C,D] -> mean over 8 consecutive c -> xs_bf [N*Q, D] ----------------
__global__ void k_pool(const float* __restrict__ x, bf16* __restrict__ xs) {
  int b = blockIdx.x;                       // N*Q*8 = 16384 blocks
  int d = (b & 7) * 256 + threadIdx.x;
  int q = (b >> 3) & 63;
  int n = b >> 9;
  const float* p = x + ((size_t)(n * CB + q * 8)) * DB + d;
  float s = 0.f;
#pragma unroll
  for (int j = 0; j < 8; ++j) s += p[(size_t)j * DB];
  xs[((size_t)(n * QB + q)) * DB + d] = __float2bfloat16(s * 0.125f);
}

// ---------------- gating ----------------
__global__ void k_gate(const bf16* __restrict__ xs, const float* __restrict__ wg,
                       float* __restrict__ gates) {
  int t = blockIdx.x * 4 + (threadIdx.x >> 6);
  int lane = threadIdx.x & 63;
  const bf16* row = xs + (size_t)t * DB;
  float z0 = 0.f, z1 = 0.f;
  for (int d = lane; d < DB; d += 64) {
    float v = __bfloat162float(row[d]);
    z0 += v * wg[d * 2];
    z1 += v * wg[d * 2 + 1];
  }
#pragma unroll
  for (int m = 32; m; m >>= 1) { z0 += __shfl_xor(z0, m, 64); z1 += __shfl_xor(z1, m, 64); }
  if (lane == 0) {
    float mx = fmaxf(z0, z1);
    float e0 = __expf(z0 - mx), e1 = __expf(z1 - mx);
    float s = e0 + e1;
    float p0 = e0 / s, p1 = e1 / s;
    float inv = 1.0f / (p0 + p1 + 1e-6f);
    gates[t * 2] = p0 * inv;
    gates[t * 2 + 1] = p1 * inv;
  }
}

// ---------------- transpose + convert: W [2048][2048] f32 -> WT [n][k] bf16 ----------------
__global__ void k_transpose(const float* __restrict__ W, bf16* __restrict__ WT) {
  __shared__ float t[32][33];
  int bx = blockIdx.x * 32;
  int by = blockIdx.y * 32;
  int tx = threadIdx.x, ty0 = threadIdx.y;
#pragma unroll
  for (int j = 0; j < 4; ++j) {
    int ty = ty0 + j * 8;
    t[ty][tx] = W[(size_t)(by + ty) * DB + bx + tx];
  }
  __syncthreads();
#pragma unroll
  for (int j = 0; j < 4; ++j) {
    int ty = ty0 + j * 8;
    WT[(size_t)(bx + ty) * DB + by + tx] = __float2bfloat16(t[tx][ty]);
  }
}

// ======== 256x256 8-phase GEMM: C[M][N] = A[M][K] @ BT[N][K]^T + bias ========
// Requires M%256==0, N%256==0, K%64==0, gridDim.x % 8 == 0.
// EPI: 0 = bf16 out, 1 = GELU->bf16, 2 = f32 out
template <int EPI>
__global__ __launch_bounds__(512, 2) void k_gemm256(
    const bf16* __restrict__ A, int lda, long long sAb,
    const bf16* __restrict__ BT, int ldb, long long sBb,
    const float* __restrict__ bias, void* __restrict__ Cout, int ldc, long long sCb,
    int K, int ntiles) {
  __shared__ __align__(16) bf16 lds[2][2][256 * 64];   // [buf][A/B][256 rows x 64 k]

  // XCD-bijective swizzle (gridDim.x % 8 == 0)
  int bid = blockIdx.x;
  { int c = gridDim.x >> 3; bid = (bid & 7) * c + (bid >> 3); }
  const int m0 = (bid / ntiles) * 256;
  const int n0 = (bid % ntiles) * 256;
  const int z = blockIdx.z;
  A += (size_t)z * sAb;
  BT += (size_t)z * sBb;

  const int tid = threadIdx.x;
  const int l = tid & 63, w = tid >> 6;      // 8 waves
  const int wr = w >> 2, wc = w & 3;         // 2 x 4 wave grid
  const int fr = l & 15, fg = l >> 4;

  // staging geometry: per wave 8 rows x 128B per round; chunk-XOR swizzle on source
  const int rloc = w * 8 + (l >> 3);                 // row within 64-row round
  const int cswz = ((l & 7) ^ (l >> 3)) * 8;         // element offset (chunk ^ row&7)
  const bf16* Asw = A + cswz;
  const bf16* Bsw = BT + cswz;

  // ds_read offsets (inverse swizzle on read: chunk ^= row&7; row&7 == fr&7 == l&7... for fr<8/8..15 use fr&7)
  int rbA[4], rbB[4], ckb[2];
#pragma unroll
  for (int mi = 0; mi < 4; ++mi) rbA[mi] = (wr * 64 + mi * 16 + fr) * 128;
#pragma unroll
  for (int ni = 0; ni < 4; ++ni) rbB[ni] = ((ni >> 1) * 128 + wc * 32 + (ni & 1) * 16 + fr) * 128;
#pragma unroll
  for (int kk = 0; kk < 2; ++kk) ckb[kk] = ((kk * 4 + fg) ^ (fr & 7)) * 16;

  f32x4 acc[8][4] = {};
  s16x8 af[4][2], bfr[4][2];

  auto stg = [&](const bf16* srcsw, int ld, int row0, int kcol, char* dst) {
    gload16(srcsw + (size_t)(row0 + rloc) * ld + kcol, dst + w * 1024);
    gload16(srcsw + (size_t)(row0 + 64 + rloc) * ld + kcol, dst + 8192 + w * 1024);
  };

  // prologue: stage tile 0 fully into buf0
  stg(Asw, lda, m0, 0, (char*)&lds[0][0][0]);
  stg(Bsw, ldb, n0, 0, (char*)&lds[0][1][0]);
  stg(Bsw, ldb, n0 + 128, 0, (char*)&lds[0][1][0] + 16384);
  stg(Asw, lda, m0 + 128, 0, (char*)&lds[0][0][0] + 16384);
  asm volatile("s_waitcnt vmcnt(0)" ::: "memory");
  BAR2;

  const int NT = K >> 6;
  for (int t = 0; t < NT; ++t) {
    const int buf = t & 1;
    const char* Ab = (const char*)&lds[buf][0][0];
    const char* Bb = (const char*)&lds[buf][1][0];
    char* As = (char*)&lds[buf ^ 1][0][0];
    char* Bs = (char*)&lds[buf ^ 1][1][0];
    const int kn = (t + 1 < NT ? (t + 1) : 0) << 6;   // wrap: last stage is harmless

    // ---- phase 0: ds_read A-half0 + B-half0 ; stage A-half0(t+1)
#pragma unroll
    for (int mi = 0; mi < 4; ++mi)
#pragma unroll
      for (int kk = 0; kk < 2; ++kk)
        af[mi][kk] = *(const s16x8*)(Ab + rbA[mi] + ckb[kk]);
#pragma unroll
    for (int ni = 0; ni < 2; ++ni)
#pragma unroll
      for (int kk = 0; kk < 2; ++kk)
        bfr[ni][kk] = *(const s16x8*)(Bb + rbB[ni] + ckb[kk]);
    stg(Asw, lda, m0, kn, As);
    BAR2;
    __builtin_amdgcn_s_setprio(1);
#pragma unroll
    for (int mi = 0; mi < 4; ++mi)
#pragma unroll
      for (int ni = 0; ni < 2; ++ni)
#pragma unroll
        for (int kk = 0; kk < 2; ++kk)
          acc[mi][ni] = __builtin_amdgcn_mfma_f32_16x16x32_bf16(af[mi][kk], bfr[ni][kk], acc[mi][ni], 0, 0, 0);
    __builtin_amdgcn_s_setprio(0);
    VM4;   // force B-half1(t) landed (for phase 1 reads)
    BAR2;

    // ---- phase 1: ds_read B-half1 ; stage B-half0(t+1)
#pragma unroll
    for (int ni = 2; ni < 4; ++ni)
#pragma unroll
      for (int kk = 0; kk < 2; ++kk)
        bfr[ni][kk] = *(const s16x8*)(Bb + rbB[ni] + ckb[kk]);
    stg(Bsw, ldb, n0, kn, Bs);
    BAR2;
    __builtin_amdgcn_s_setprio(1);
#pragma unroll
    for (int mi = 0; mi < 4; ++mi)
#pragma unroll
      for (int ni = 2; ni < 4; ++ni)
#pragma unroll
        for (int kk = 0; kk < 2; ++kk)
          acc[mi][ni] = __builtin_amdgcn_mfma_f32_16x16x32_bf16(af[mi][kk], bfr[ni][kk], acc[mi][ni], 0, 0, 0);
    __builtin_amdgcn_s_setprio(0);
    VM4;   // force A-half1(t) landed (for phase 2 reads)
    BAR2;

    // ---- phase 2: ds_read A-half1 ; stage B-half1(t+1)
#pragma unroll
    for (int mi = 0; mi < 4; ++mi)
#pragma unroll
      for (int kk = 0; kk < 2; ++kk)
        af[mi][kk] = *(const s16x8*)(Ab + 16384 + rbA[mi] + ckb[kk]);
    stg(Bsw, ldb, n0 + 128, kn, Bs + 16384);
    BAR2;
    __builtin_amdgcn_s_setprio(1);
#pragma unroll
    for (int mi = 0; mi < 4; ++mi)
#pragma unroll
      for (int ni = 0; ni < 2; ++ni)
#pragma unroll
        for (int kk = 0; kk < 2; ++kk)
          acc[4 + mi][ni] = __builtin_amdgcn_mfma_f32_16x16x32_bf16(af[mi][kk], bfr[ni][kk], acc[4 + mi][ni], 0, 0, 0);
    __builtin_amdgcn_s_setprio(0);
    BAR2;  // no vmcnt needed (phase 3 has no ds_reads)

    // ---- phase 3: stage A-half1(t+1)
    stg(Asw, lda, m0 + 128, kn, As + 16384);
    BAR2;
    __builtin_amdgcn_s_setprio(1);
#pragma unroll
    for (int mi = 0; mi < 4; ++mi)
#pragma unroll
      for (int ni = 2; ni < 4; ++ni)
#pragma unroll
        for (int kk = 0; kk < 2; ++kk)
          acc[4 + mi][ni] = __builtin_amdgcn_mfma_f32_16x16x32_bf16(af[mi][kk], bfr[ni][kk], acc[4 + mi][ni], 0, 0, 0);
    __builtin_amdgcn_s_setprio(0);
    VM4;   // force A-half0(t+1), B-half0(t+1) landed (for next phase 0 reads)
    BAR2;
  }

  // epilogue
#pragma unroll
  for (int mi = 0; mi < 8; ++mi) {
    int row = m0 + (mi >> 2) * 128 + wr * 64 + (mi & 3) * 16 + fg * 4;
#pragma unroll
    for (int ni = 0; ni < 4; ++ni) {
      int col = n0 + (ni >> 1) * 128 + wc * 32 + (ni & 1) * 16 + fr;
      float bv = bias ? bias[col] : 0.f;
#pragma unroll
      for (int j = 0; j < 4; ++j) {
        float v = acc[mi][ni][j] + bv;
        size_t o = (size_t)z * sCb + (size_t)(row + j) * ldc + col;
        if (EPI == 0) {
          ((bf16*)Cout)[o] = __float2bfloat16(v);
        } else if (EPI == 1) {
          ((bf16*)Cout)[o] = __float2bfloat16(gelu_f(v));
        } else {
          ((float*)Cout)[o] = v;
        }
      }
    }
  }
}

// ---------------- 128x128 GEMM (small shapes: q-proj, qk, out-proj) ----------------
template <int EPI>
__global__ __launch_bounds__(256) void k_gemm(
    const bf16* __restrict__ A, int lda, long long sAb,
    const bf16* __restrict__ BT, int ldb, long long sBb,
    const float* __restrict__ bias, void* __restrict__ Cout, int ldc, long long sCb,
    int M, int K) {
  __shared__ bf16 As[128 * 32];
  __shared__ bf16 Bs[128 * 32];
  const int z = blockIdx.z;
  A += (size_t)z * sAb;
  BT += (size_t)z * sBb;
  const int tid = threadIdx.x;
  const int lane = tid & 63, w = tid >> 6;
  const int m0 = blockIdx.x * 128, n0 = blockIdx.y * 128;
  const int wm = (w >> 1) * 64, wn = (w & 1) * 64;
  f32x4 acc[4][4] = {};

  const int srow = tid >> 2;
  const int scol = (tid & 3) * 8;
  int gr0 = m0 + srow;       if (gr0 > M - 1) gr0 = M - 1;
  int gr1 = m0 + 64 + srow;  if (gr1 > M - 1) gr1 = M - 1;
  const bf16* ag0 = A + (size_t)gr0 * lda + scol;
  const bf16* ag1 = A + (size_t)gr1 * lda + scol;
  const bf16* bg0 = BT + (size_t)(n0 + srow) * ldb + scol;
  const bf16* bg1 = BT + (size_t)(n0 + 64 + srow) * ldb + scol;
  char* lA = (char*)As + w * 1024;
  char* lB = (char*)Bs + w * 1024;

  const int fr = lane & 15, fk = (lane >> 4) * 8;

  for (int k0 = 0; k0 < K; k0 += 32) {
    __syncthreads();
    gload16(ag0 + k0, lA);
    gload16(ag1 + k0, lA + 4096);
    gload16(bg0 + k0, lB);
    gload16(bg1 + k0, lB + 4096);
    __syncthreads();
    s16x8 af[4], bfr[4];
#pragma unroll
    for (int i = 0; i < 4; ++i)
      af[i] = *(const s16x8*)(As + (wm + i * 16 + fr) * 32 + fk);
#pragma unroll
    for (int i = 0; i < 4; ++i)
      bfr[i] = *(const s16x8*)(Bs + (wn + i * 16 + fr) * 32 + fk);
#pragma unroll
    for (int mi = 0; mi < 4; ++mi)
#pragma unroll
      for (int ni = 0; ni < 4; ++ni)
        acc[mi][ni] = __builtin_amdgcn_mfma_f32_16x16x32_bf16(af[mi], bfr[ni], acc[mi][ni], 0, 0, 0);
  }

  const int fg4 = (lane >> 4) * 4;
#pragma unroll
  for (int mi = 0; mi < 4; ++mi) {
#pragma unroll
    for (int ni = 0; ni < 4; ++ni) {
      int col = n0 + wn + ni * 16 + fr;
      float bv = bias ? bias[col] : 0.f;
#pragma unroll
      for (int j = 0; j < 4; ++j) {
        int r = m0 + wm + mi * 16 + fg4 + j;
        if (r >= M) continue;
        float v = acc[mi][ni][j] + bv;
        size_t o = (size_t)z * sCb + (size_t)r * ldc + col;
        if (EPI == 0) {
          ((bf16*)Cout)[o] = __float2bfloat16(v);
        } else if (EPI == 1) {
          ((bf16*)Cout)[o] = __float2bfloat16(gelu_f(v));
        } else {
          ((float*)Cout)[o] = v;
        }
      }
    }
  }
}

// ---------------- attention per (n,h): precomputed scores S [N][H*Q][C], V staged, PV ----
__global__ __launch_bounds__(256) void k_attn(
    const bf16* __restrict__ S, const bf16* __restrict__ Vg, bf16* __restrict__ ctxg) {
  __shared__ bf16 vt[128 * 64];
  __shared__ bf16 pb[4][16 * 64];
  const int nh = blockIdx.x;
  const int n = nh >> 4, h = nh & 15;
  const int tid = threadIdx.x, lane = tid & 63, w = tid >> 6;
  const int fr = lane & 15, fg = lane >> 4;

  f32x4 ctx[8] = {};
  float mrow[4], lrow[4];
#pragma unroll
  for (int j = 0; j < 4; ++j) { mrow[j] = -1e30f; lrow[j] = 0.f; }

  const bf16* Srow = S + ((size_t)n * (HB * QB) + h * QB) * CB;  // [64][512]
  const bf16* Vbase = Vg + (size_t)(n * CB) * DB + h * DHB;
  const float SC = 0.08838834764831845f;   // 1/sqrt(128)

  const int krow = tid >> 4;          // 0..15
  const int kcol = (tid & 15) * 8;

  for (int c0 = 0; c0 < CB; c0 += 64) {
    __syncthreads();
#pragma unroll
    for (int jj = 0; jj < 4; ++jj) {
      int row = jj * 16 + krow;
      s16x8 vv = *(const s16x8*)(Vbase + (size_t)(c0 + row) * DB + kcol);
#pragma unroll
      for (int i = 0; i < 8; ++i)
        vt[(kcol + i) * 64 + row] = ((const bf16*)&vv)[i];
    }

    f32x4 s4[4];
#pragma unroll
    for (int ci = 0; ci < 4; ++ci)
#pragma unroll
      for (int j = 0; j < 4; ++j)
        s4[ci][j] = __bfloat162float(Srow[(size_t)(w * 16 + fg * 4 + j) * CB + c0 + ci * 16 + fr]);

#pragma unroll
    for (int j = 0; j < 4; ++j) {
      float m = fmaxf(fmaxf(s4[0][j], s4[1][j]), fmaxf(s4[2][j], s4[3][j])) * SC;
#pragma unroll
      for (int msk = 1; msk < 16; msk <<= 1) m = fmaxf(m, __shfl_xor(m, msk, 16));
      float newm = fmaxf(mrow[j], m);
      float resc = __expf(mrow[j] - newm);
      mrow[j] = newm;
      float rsum = 0.f;
#pragma unroll
      for (int ci = 0; ci < 4; ++ci) {
        float p = __expf(s4[ci][j] * SC - newm);
        rsum += p;
        pb[w][(fg * 4 + j) * 64 + ci * 16 + fr] = __float2bfloat16(p);
      }
#pragma unroll
      for (int msk = 1; msk < 16; msk <<= 1) rsum += __shfl_xor(rsum, msk, 16);
      lrow[j] = lrow[j] * resc + rsum;
#pragma unroll
      for (int ni = 0; ni < 8; ++ni) ctx[ni][j] = ctx[ni][j] * resc;
    }
    __syncthreads();

#pragma unroll
    for (int kk2 = 0; kk2 < 2; ++kk2) {
      s16x8 pa = *(const s16x8*)(&pb[w][fr * 64 + kk2 * 32 + fg * 8]);
#pragma unroll
      for (int ni = 0; ni < 8; ++ni) {
        s16x8 bv = *(const s16x8*)(vt + (ni * 16 + fr) * 64 + kk2 * 32 + fg * 8);
        ctx[ni] = __builtin_amdgcn_mfma_f32_16x16x32_bf16(pa, bv, ctx[ni], 0, 0, 0);
      }
    }
  }

#pragma unroll
  for (int ni = 0; ni < 8; ++ni) {
#pragma unroll
    for (int j = 0; j < 4; ++j) {
      int q = w * 16 + fg * 4 + j;
      float v = ctx[ni][j] / lrow[j];
      ctxg[(size_t)(n * QB + q) * DB + h * DHB + ni * 16 + fr] = __float2bfloat16(v);
    }
  }
}

// ---------------- gated combine ----------------
__global__ void k_combine(const float* __restrict__ e01, const float* __restrict__ gates,
                          float* __restrict__ out) {
  int i = blockIdx.x * blockDim.x + threadIdx.x;
  int t = i >> 9;
  float4 a = ((const float4*)e01)[i];
  float4 b = ((const float4*)e01)[i + (1 << 20)];
  float g0 = gates[t * 2], g1 = gates[t * 2 + 1];
  float4 o;
  o.x = a.x * g0 + b.x * g1;
  o.y = a.y * g0 + b.y * g1;
  o.z = a.z * g0 + b.z * g1;
  o.w = a.w * g0 + b.w * g1;
  ((float4*)out)[i] = o;
}

extern "C" void kernel_launch(void* const* d_in, const int* in_sizes, int n_in,
                              void* d_out, int out_size, void* d_ws, size_t ws_size,
                              hipStream_t stream) {
  const float* x  = (const float*)d_in[0];
  const float* w1 = (const float*)d_in[1];
  const float* b1 = (const float*)d_in[2];
  const float* w2 = (const float*)d_in[3];
  const float* b2 = (const float*)d_in[4];
  const float* qt = (const float*)d_in[5];
  const float* wq = (const float*)d_in[6];
  const float* bq = (const float*)d_in[7];
  const float* wk = (const float*)d_in[8];
  const float* wv = (const float*)d_in[10];
  const float* bv = (const float*)d_in[11];
  const float* wo = (const float*)d_in[12];
  const float* bo = (const float*)d_in[13];
  const float* wg = (const float*)d_in[14];
  float* out = (float*)d_out;

  char* ws = (char*)d_ws;
  size_t off = 0;
  auto alloc = [&](size_t bytes) {
    char* p = ws + off;
    off += (bytes + 255) & ~(size_t)255;
    return p;
  };
  const size_t XE = (size_t)NB * CB * DB;
  const size_t WE = (size_t)DB * DB;
  const size_t TE = (size_t)NB * QB * DB;

  bf16* x_bf   = (bf16*)alloc(XE * 2);
  bf16* V_bf   = (bf16*)alloc(XE * 2);
  bf16* wk_bf  = (bf16*)alloc(WE * 2);
  bf16* w1T    = (bf16*)alloc(WE * 2);
  bf16* w2T    = (bf16*)alloc(WE * 2);
  bf16* wvT    = (bf16*)alloc(WE * 2);
  bf16* wqT    = (bf16*)alloc(WE * 2);
  bf16* woT    = (bf16*)alloc(WE * 2);
  bf16* tokens = (bf16*)alloc(2 * TE * 2);
  bf16* h4     = (bf16*)alloc(2 * TE * 2);
  float* e01   = (float*)alloc(2 * TE * 4);
  bf16* ctx_bf = (bf16*)alloc(TE * 2);
  bf16* qt_bf  = (bf16*)alloc((size_t)QB * DB * 2);
  bf16* qproj  = (bf16*)alloc((size_t)QB * DB * 2);
  bf16* qk     = (bf16*)alloc((size_t)HB * QB * DB * 2);
  bf16* Sbuf   = (bf16*)alloc((size_t)NB * HB * QB * CB * 2);
  float* gates = (float*)alloc((size_t)NB * QB * 2 * 4);
  (void)ws_size; (void)in_sizes; (void)n_in; (void)out_size;

  k_convert<<<2048, 256, 0, stream>>>(x, (unsigned short*)x_bf, (int)(XE / 4));
  k_convert<<<64, 256, 0, stream>>>(qt, (unsigned short*)qt_bf, (int)(QB * DB / 4));
  k_convert<<<1024, 256, 0, stream>>>(wk, (unsigned short*)wk_bf, (int)(WE / 4));
  k_pool<<<NB * QB * 8, 256, 0, stream>>>(x, tokens);
  k_gate<<<NB * QB / 4, 256, 0, stream>>>(tokens, wg, gates);

  dim3 tb(32, 8), tg(64, 64);
  k_transpose<<<tg, tb, 0, stream>>>(w1, w1T);
  k_transpose<<<tg, tb, 0, stream>>>(w2, w2T);
  k_transpose<<<tg, tb, 0, stream>>>(wv, wvT);
  k_transpose<<<tg, tb, 0, stream>>>(wq, wqT);
  k_transpose<<<tg, tb, 0, stream>>>(wo, woT);

  // q projection (small, 128^2 kernel)
  k_gemm<0><<<dim3(1, 16, 1), 256, 0, stream>>>(
      qt_bf, DB, 0, wqT, DB, 0, bq, qproj, DB, 0, QB, DB);

  // qk[h][q][d] = sum_dh qproj[q, h*128+dh] * wk[d, h*128+dh]
  k_gemm<0><<<dim3(1, 16, HB), 256, 0, stream>>>(
      qproj, DB, DHB, wk_bf, DB, DHB, nullptr, qk, DB, (long long)QB * DB, QB, DHB);

  // V projection (256^2 8-phase)
  k_gemm256<0><<<dim3(512, 1, 1), 512, 0, stream>>>(
      x_bf, DB, 0, wvT, DB, 0, bv, V_bf, DB, 0, DB, 8);

  // scores: S[n] = qk @ x[n]^T (256^2 8-phase, batched over n)
  k_gemm256<0><<<dim3(8, 1, NB), 512, 0, stream>>>(
      qk, DB, 0, x_bf, DB, (long long)CB * DB, nullptr,
      Sbuf, CB, (long long)HB * QB * CB, DB, 2);

  // cross attention (softmax + PV)
  k_attn<<<NB * HB, 256, 0, stream>>>(Sbuf, V_bf, ctx_bf);

  // output proj -> tokens rows 2048..4095 (128^2 kernel, 256 blocks)
  k_gemm<0><<<dim3(16, 16, 1), 256, 0, stream>>>(
      ctx_bf, DB, 0, woT, DB, 0, bo, tokens + (size_t)2048 * DB, DB, 0, 2048, DB);

  // stacked expert MLP on [xs; res] (256^2 8-phase)
  k_gemm256<1><<<dim3(128, 1, 1), 512, 0, stream>>>(
      tokens, DB, 0, w1T, DB, 0, b1, h4, DB, 0, DB, 8);
  k_gemm256<2><<<dim3(128, 1, 1), 512, 0, stream>>>(
      h4, DB, 0, w2T, DB, 0, b2, e01, DB, 0, DB, 8);

  k_combine<<<4096, 256, 0, stream>>>(e01, gates, out);
}

// Round 4
// 552.543 us; speedup vs baseline: 1.6951x; 1.1246x over previous
//
#include <hip/hip_runtime.h>
#include <hip/hip_bf16.h>

typedef float f32x4 __attribute__((ext_vector_type(4)));
typedef short s16x8 __attribute__((ext_vector_type(8)));
typedef __hip_bfloat16 bf16;

#define NB 32
#define CB 512
#define DB 2048
#define QB 64
#define HB 16
#define DHB 128

static __device__ __forceinline__ void gload16(const void* g, void* l) {
  __builtin_amdgcn_global_load_lds(
      (const __attribute__((address_space(1))) void*)g,
      (__attribute__((address_space(3))) void*)l, 16, 0, 0);
}

static __device__ __forceinline__ unsigned short f2bf(float f) {
  bf16 b = __float2bfloat16(f);
  return *reinterpret_cast<unsigned short*>(&b);
}

static __device__ __forceinline__ float gelu_f(float z) {
  return 0.5f * z * (1.0f + erff(z * 0.7071067811865475f));
}

#define BAR2 do { asm volatile("" ::: "memory"); __builtin_amdgcn_s_barrier(); asm volatile("" ::: "memory"); } while (0)
#define VM2  asm volatile("s_waitcnt vmcnt(2)" ::: "memory")

// ---------------- fused convert+pool: x f32 -> x_bf + pooled xs ----------------
// grid (4, 64, 32), block 256; each thread handles 2 d-elems over 8 c-rows.
__global__ void k_convpool(const float* __restrict__ x, bf16* __restrict__ x_bf,
                           bf16* __restrict__ xs) {
  const int d0 = blockIdx.x * 512 + threadIdx.x * 2;
  const int q = blockIdx.y, n = blockIdx.z;
  const size_t base = ((size_t)(n * CB + q * 8)) * DB + d0;
  float s0 = 0.f, s1 = 0.f;
#pragma unroll
  for (int j = 0; j < 8; ++j) {
    float2 v = *(const float2*)(x + base + (size_t)j * DB);
    s0 += v.x; s1 += v.y;
    ushort2 o; o.x = f2bf(v.x); o.y = f2bf(v.y);
    *(ushort2*)((unsigned short*)x_bf + base + (size_t)j * DB) = o;
  }
  ushort2 p; p.x = f2bf(s0 * 0.125f); p.y = f2bf(s1 * 0.125f);
  *(ushort2*)((unsigned short*)xs + ((size_t)(n * QB + q)) * DB + d0) = p;
}

// ---------------- convert f32 -> bf16 ----------------
__global__ void k_convert(const float* __restrict__ in, unsigned short* __restrict__ out, int n4) {
  int stride = gridDim.x * blockDim.x;
  for (int i = blockIdx.x * blockDim.x + threadIdx.x; i < n4; i += stride) {
    float4 v = ((const float4*)in)[i];
    ushort4 o;
    o.x = f2bf(v.x); o.y = f2bf(v.y); o.z = f2bf(v.z); o.w = f2bf(v.w);
    ((ushort4*)out)[i] = o;
  }
}

// ---------------- gating ----------------
__global__ void k_gate(const bf16* __restrict__ xs, const float* __restrict__ wg,
                       float* __restrict__ gates) {
  int t = blockIdx.x * 4 + (threadIdx.x >> 6);
  int lane = threadIdx.x & 63;
  const bf16* row = xs + (size_t)t * DB;
  float z0 = 0.f, z1 = 0.f;
  for (int d = lane; d < DB; d += 64) {
    float v = __bfloat162float(row[d]);
    z0 += v * wg[d * 2];
    z1 += v * wg[d * 2 + 1];
  }
#pragma unroll
  for (int m = 32; m; m >>= 1) { z0 += __shfl_xor(z0, m, 64); z1 += __shfl_xor(z1, m, 64); }
  if (lane == 0) {
    float mx = fmaxf(z0, z1);
    float e0 = __expf(z0 - mx), e1 = __expf(z1 - mx);
    float s = e0 + e1;
    float p0 = e0 / s, p1 = e1 / s;
    float inv = 1.0f / (p0 + p1 + 1e-6f);
    gates[t * 2] = p0 * inv;
    gates[t * 2 + 1] = p1 * inv;
  }
}

// ---------------- batched transpose+convert: 5 weights in one launch ----------------
struct TP5 { const float* s[5]; bf16* d[5]; };
__global__ void k_transpose5(TP5 p) {
  __shared__ float t[32][33];
  const float* W = p.s[blockIdx.z];
  bf16* WT = p.d[blockIdx.z];
  int bx = blockIdx.x * 32;
  int by = blockIdx.y * 32;
  int tx = threadIdx.x, ty0 = threadIdx.y;
#pragma unroll
  for (int j = 0; j < 4; ++j) {
    int ty = ty0 + j * 8;
    t[ty][tx] = W[(size_t)(by + ty) * DB + bx + tx];
  }
  __syncthreads();
#pragma unroll
  for (int j = 0; j < 4; ++j) {
    int ty = ty0 + j * 8;
    WT[(size_t)(bx + ty) * DB + by + tx] = __float2bfloat16(t[tx][ty]);
  }
}

// ======== 256x256 GEMM, 2-barrier/K-tile, K-split phases ========
// C[M][N] = A[M][K] @ BT[N][K]^T + bias. M%256==0, N%256==0, K%64==0.
// EPI: 0 = bf16 out, 1 = GELU->bf16, 2 = f32 out
template <int EPI>
__global__ __launch_bounds__(512, 2) void k_gemm256(
    const bf16* __restrict__ A, int lda, long long sAb,
    const bf16* __restrict__ BT, int ldb, long long sBb,
    const float* __restrict__ bias, void* __restrict__ Cout, int ldc, long long sCb,
    int K, int ntiles) {
  __shared__ __align__(16) bf16 lds[2][2][256 * 64];   // [buf][A/B][128B rows]

  int bid = blockIdx.x;
  { int c = gridDim.x >> 3; bid = (bid & 7) * c + (bid >> 3); }
  const int m0 = (bid / ntiles) * 256;
  const int n0 = (bid % ntiles) * 256;
  const int z = blockIdx.z;
  A += (size_t)z * sAb;
  BT += (size_t)z * sBb;

  const int tid = threadIdx.x;
  const int l = tid & 63, w = tid >> 6;
  const int wr = w >> 2, wc = w & 3;
  const int fr = l & 15, fg = l >> 4;

  const int rloc = w * 8 + (l >> 3);
  const int cswz = ((l & 7) ^ (l >> 3)) * 8;   // source-side swizzle (involution)
  const bf16* Asw = A + cswz;
  const bf16* Bsw = BT + cswz;

  int rbA[4], rbB[4], ckb[2];
#pragma unroll
  for (int mi = 0; mi < 4; ++mi) rbA[mi] = (wr * 64 + mi * 16 + fr) * 128;
#pragma unroll
  for (int ni = 0; ni < 4; ++ni) rbB[ni] = ((ni >> 1) * 128 + wc * 32 + (ni & 1) * 16 + fr) * 128;
#pragma unroll
  for (int kk = 0; kk < 2; ++kk) ckb[kk] = ((kk * 4 + fg) ^ (fr & 7)) * 16;

  f32x4 acc[8][4] = {};
  s16x8 af[4], bfr[4][2];

  auto stg = [&](const bf16* srcsw, int ld, int row0, int kcol, char* dst) {
    gload16(srcsw + (size_t)(row0 + rloc) * ld + kcol, dst + w * 1024);
    gload16(srcsw + (size_t)(row0 + 64 + rloc) * ld + kcol, dst + 8192 + w * 1024);
  };

  // prologue: stage tile 0 fully into buf0
  stg(Asw, lda, m0, 0, (char*)&lds[0][0][0]);
  stg(Bsw, ldb, n0, 0, (char*)&lds[0][1][0]);
  stg(Bsw, ldb, n0 + 128, 0, (char*)&lds[0][1][0] + 16384);
  stg(Asw, lda, m0 + 128, 0, (char*)&lds[0][0][0] + 16384);
  asm volatile("s_waitcnt vmcnt(0)" ::: "memory");
  BAR2;

  const int NT = K >> 6;
  for (int t = 0; t < NT; ++t) {
    const int buf = t & 1;
    const char* Ab = (const char*)&lds[buf][0][0];
    const char* Bb = (const char*)&lds[buf][1][0];
    char* As = (char*)&lds[buf ^ 1][0][0];
    char* Bs = (char*)&lds[buf ^ 1][1][0];
    const int kn = (t + 1 < NT ? (t + 1) : 0) << 6;

    // ---- segment B (phase 0): Mlo x Nall x k0
    stg(Asw, lda, m0, kn, As);                         // A-lo(t+1)
#pragma unroll
    for (int mi = 0; mi < 4; ++mi) af[mi] = *(const s16x8*)(Ab + rbA[mi] + ckb[0]);
#pragma unroll
    for (int ni = 0; ni < 4; ++ni) bfr[ni][0] = *(const s16x8*)(Bb + rbB[ni] + ckb[0]);
    __builtin_amdgcn_s_setprio(1);
#pragma unroll
    for (int mi = 0; mi < 4; ++mi)
#pragma unroll
      for (int ni = 0; ni < 4; ++ni)
        acc[mi][ni] = __builtin_amdgcn_mfma_f32_16x16x32_bf16(af[mi], bfr[ni][0], acc[mi][ni], 0, 0, 0);
    __builtin_amdgcn_s_setprio(0);
    VM2;   // publish A-hi(t); leaves A-lo(t+1) in flight
    BAR2;

    // ---- segment A (phases 1-3)
    // p1: Mhi x Nall x k0
    stg(Bsw, ldb, n0, kn, Bs);                         // B-lo(t+1)
#pragma unroll
    for (int mi = 0; mi < 4; ++mi) af[mi] = *(const s16x8*)(Ab + 16384 + rbA[mi] + ckb[0]);
    __builtin_amdgcn_s_setprio(1);
#pragma unroll
    for (int mi = 0; mi < 4; ++mi)
#pragma unroll
      for (int ni = 0; ni < 4; ++ni)
        acc[4 + mi][ni] = __builtin_amdgcn_mfma_f32_16x16x32_bf16(af[mi], bfr[ni][0], acc[4 + mi][ni], 0, 0, 0);
    __builtin_amdgcn_s_setprio(0);

    // p2: Mlo x Nall x k1
    stg(Bsw, ldb, n0 + 128, kn, Bs + 16384);           // B-hi(t+1)
#pragma unroll
    for (int mi = 0; mi < 4; ++mi) af[mi] = *(const s16x8*)(Ab + rbA[mi] + ckb[1]);
#pragma unroll
    for (int ni = 0; ni < 4; ++ni) bfr[ni][1] = *(const s16x8*)(Bb + rbB[ni] + ckb[1]);
    __builtin_amdgcn_s_setprio(1);
#pragma unroll
    for (int mi = 0; mi < 4; ++mi)
#pragma unroll
      for (int ni = 0; ni < 4; ++ni)
        acc[mi][ni] = __builtin_amdgcn_mfma_f32_16x16x32_bf16(af[mi], bfr[ni][1], acc[mi][ni], 0, 0, 0);
    __builtin_amdgcn_s_setprio(0);

    // p3: Mhi x Nall x k1
    stg(Asw, lda, m0 + 128, kn, As + 16384);           // A-hi(t+1)
#pragma unroll
    for (int mi = 0; mi < 4; ++mi) af[mi] = *(const s16x8*)(Ab + 16384 + rbA[mi] + ckb[1]);
    __builtin_amdgcn_s_setprio(1);
#pragma unroll
    for (int mi = 0; mi < 4; ++mi)
#pragma unroll
      for (int ni = 0; ni < 4; ++ni)
        acc[4 + mi][ni] = __builtin_amdgcn_mfma_f32_16x16x32_bf16(af[mi], bfr[ni][1], acc[4 + mi][ni], 0, 0, 0);
    __builtin_amdgcn_s_setprio(0);
    VM2;   // publish A-lo,B-lo,B-hi(t+1); leaves A-hi(t+1) in flight
    BAR2;
  }

  // epilogue
#pragma unroll
  for (int mi = 0; mi < 8; ++mi) {
    int row = m0 + (mi >> 2) * 128 + wr * 64 + (mi & 3) * 16 + fg * 4;
#pragma unroll
    for (int ni = 0; ni < 4; ++ni) {
      int col = n0 + (ni >> 1) * 128 + wc * 32 + (ni & 1) * 16 + fr;
      float bv = bias ? bias[col] : 0.f;
#pragma unroll
      for (int j = 0; j < 4; ++j) {
        float v = acc[mi][ni][j] + bv;
        size_t o = (size_t)z * sCb + (size_t)(row + j) * ldc + col;
        if (EPI == 0) {
          ((bf16*)Cout)[o] = __float2bfloat16(v);
        } else if (EPI == 1) {
          ((bf16*)Cout)[o] = __float2bfloat16(gelu_f(v));
        } else {
          ((float*)Cout)[o] = v;
        }
      }
    }
  }
}

// ---------------- 128x128 GEMM (small shapes: q-proj, qk) ----------------
template <int EPI>
__global__ __launch_bounds__(256) void k_gemm(
    const bf16* __restrict__ A, int lda, long long sAb,
    const bf16* __restrict__ BT, int ldb, long long sBb,
    const float* __restrict__ bias, void* __restrict__ Cout, int ldc, long long sCb,
    int M, int K) {
  __shared__ bf16 As[128 * 32];
  __shared__ bf16 Bs[128 * 32];
  const int z = blockIdx.z;
  A += (size_t)z * sAb;
  BT += (size_t)z * sBb;
  const int tid = threadIdx.x;
  const int lane = tid & 63, w = tid >> 6;
  const int m0 = blockIdx.x * 128, n0 = blockIdx.y * 128;
  const int wm = (w >> 1) * 64, wn = (w & 1) * 64;
  f32x4 acc[4][4] = {};

  const int srow = tid >> 2;
  const int scol = (tid & 3) * 8;
  int gr0 = m0 + srow;       if (gr0 > M - 1) gr0 = M - 1;
  int gr1 = m0 + 64 + srow;  if (gr1 > M - 1) gr1 = M - 1;
  const bf16* ag0 = A + (size_t)gr0 * lda + scol;
  const bf16* ag1 = A + (size_t)gr1 * lda + scol;
  const bf16* bg0 = BT + (size_t)(n0 + srow) * ldb + scol;
  const bf16* bg1 = BT + (size_t)(n0 + 64 + srow) * ldb + scol;
  char* lA = (char*)As + w * 1024;
  char* lB = (char*)Bs + w * 1024;

  const int fr = lane & 15, fk = (lane >> 4) * 8;

  for (int k0 = 0; k0 < K; k0 += 32) {
    __syncthreads();
    gload16(ag0 + k0, lA);
    gload16(ag1 + k0, lA + 4096);
    gload16(bg0 + k0, lB);
    gload16(bg1 + k0, lB + 4096);
    __syncthreads();
    s16x8 af[4], bfr[4];
#pragma unroll
    for (int i = 0; i < 4; ++i)
      af[i] = *(const s16x8*)(As + (wm + i * 16 + fr) * 32 + fk);
#pragma unroll
    for (int i = 0; i < 4; ++i)
      bfr[i] = *(const s16x8*)(Bs + (wn + i * 16 + fr) * 32 + fk);
#pragma unroll
    for (int mi = 0; mi < 4; ++mi)
#pragma unroll
      for (int ni = 0; ni < 4; ++ni)
        acc[mi][ni] = __builtin_amdgcn_mfma_f32_16x16x32_bf16(af[mi], bfr[ni], acc[mi][ni], 0, 0, 0);
  }

  const int fg4 = (lane >> 4) * 4;
#pragma unroll
  for (int mi = 0; mi < 4; ++mi) {
#pragma unroll
    for (int ni = 0; ni < 4; ++ni) {
      int col = n0 + wn + ni * 16 + fr;
      float bv = bias ? bias[col] : 0.f;
#pragma unroll
      for (int j = 0; j < 4; ++j) {
        int r = m0 + wm + mi * 16 + fg4 + j;
        if (r >= M) continue;
        float v = acc[mi][ni][j] + bv;
        size_t o = (size_t)z * sCb + (size_t)r * ldc + col;
        if (EPI == 0) {
          ((bf16*)Cout)[o] = __float2bfloat16(v);
        } else if (EPI == 1) {
          ((bf16*)Cout)[o] = __float2bfloat16(gelu_f(v));
        } else {
          ((float*)Cout)[o] = v;
        }
      }
    }
  }
}

// ---------------- attention per (n,h): precomputed scores S, V staged, PV ----
__global__ __launch_bounds__(256) void k_attn(
    const bf16* __restrict__ S, const bf16* __restrict__ Vg, bf16* __restrict__ ctxg) {
  __shared__ bf16 vt[128 * 64];
  __shared__ bf16 pb[4][16 * 64];
  const int nh = blockIdx.x;
  const int n = nh >> 4, h = nh & 15;
  const int tid = threadIdx.x, lane = tid & 63, w = tid >> 6;
  const int fr = lane & 15, fg = lane >> 4;

  f32x4 ctx[8] = {};
  float mrow[4], lrow[4];
#pragma unroll
  for (int j = 0; j < 4; ++j) { mrow[j] = -1e30f; lrow[j] = 0.f; }

  const bf16* Srow = S + ((size_t)n * (HB * QB) + h * QB) * CB;
  const bf16* Vbase = Vg + (size_t)(n * CB) * DB + h * DHB;
  const float SC = 0.08838834764831845f;

  const int krow = tid >> 4;
  const int kcol = (tid & 15) * 8;

  for (int c0 = 0; c0 < CB; c0 += 64) {
    __syncthreads();
#pragma unroll
    for (int jj = 0; jj < 4; ++jj) {
      int row = jj * 16 + krow;
      s16x8 vv = *(const s16x8*)(Vbase + (size_t)(c0 + row) * DB + kcol);
#pragma unroll
      for (int i = 0; i < 8; ++i)
        vt[(kcol + i) * 64 + row] = ((const bf16*)&vv)[i];
    }

    f32x4 s4[4];
#pragma unroll
    for (int ci = 0; ci < 4; ++ci)
#pragma unroll
      for (int j = 0; j < 4; ++j)
        s4[ci][j] = __bfloat162float(Srow[(size_t)(w * 16 + fg * 4 + j) * CB + c0 + ci * 16 + fr]);

#pragma unroll
    for (int j = 0; j < 4; ++j) {
      float m = fmaxf(fmaxf(s4[0][j], s4[1][j]), fmaxf(s4[2][j], s4[3][j])) * SC;
#pragma unroll
      for (int msk = 1; msk < 16; msk <<= 1) m = fmaxf(m, __shfl_xor(m, msk, 16));
      float newm = fmaxf(mrow[j], m);
      float resc = __expf(mrow[j] - newm);
      mrow[j] = newm;
      float rsum = 0.f;
#pragma unroll
      for (int ci = 0; ci < 4; ++ci) {
        float p = __expf(s4[ci][j] * SC - newm);
        rsum += p;
        pb[w][(fg * 4 + j) * 64 + ci * 16 + fr] = __float2bfloat16(p);
      }
#pragma unroll
      for (int msk = 1; msk < 16; msk <<= 1) rsum += __shfl_xor(rsum, msk, 16);
      lrow[j] = lrow[j] * resc + rsum;
#pragma unroll
      for (int ni = 0; ni < 8; ++ni) ctx[ni][j] = ctx[ni][j] * resc;
    }
    __syncthreads();

#pragma unroll
    for (int kk2 = 0; kk2 < 2; ++kk2) {
      s16x8 pa = *(const s16x8*)(&pb[w][fr * 64 + kk2 * 32 + fg * 8]);
#pragma unroll
      for (int ni = 0; ni < 8; ++ni) {
        s16x8 bv = *(const s16x8*)(vt + (ni * 16 + fr) * 64 + kk2 * 32 + fg * 8);
        ctx[ni] = __builtin_amdgcn_mfma_f32_16x16x32_bf16(pa, bv, ctx[ni], 0, 0, 0);
      }
    }
  }

#pragma unroll
  for (int ni = 0; ni < 8; ++ni) {
#pragma unroll
    for (int j = 0; j < 4; ++j) {
      int q = w * 16 + fg * 4 + j;
      float v = ctx[ni][j] / lrow[j];
      ctxg[(size_t)(n * QB + q) * DB + h * DHB + ni * 16 + fr] = __float2bfloat16(v);
    }
  }
}

// ---------------- gated combine ----------------
__global__ void k_combine(const float* __restrict__ e01, const float* __restrict__ gates,
                          float* __restrict__ out) {
  int i = blockIdx.x * blockDim.x + threadIdx.x;
  int t = i >> 9;
  float4 a = ((const float4*)e01)[i];
  float4 b = ((const float4*)e01)[i + (1 << 20)];
  float g0 = gates[t * 2], g1 = gates[t * 2 + 1];
  float4 o;
  o.x = a.x * g0 + b.x * g1;
  o.y = a.y * g0 + b.y * g1;
  o.z = a.z * g0 + b.z * g1;
  o.w = a.w * g0 + b.w * g1;
  ((float4*)out)[i] = o;
}

extern "C" void kernel_launch(void* const* d_in, const int* in_sizes, int n_in,
                              void* d_out, int out_size, void* d_ws, size_t ws_size,
                              hipStream_t stream) {
  const float* x  = (const float*)d_in[0];
  const float* w1 = (const float*)d_in[1];
  const float* b1 = (const float*)d_in[2];
  const float* w2 = (const float*)d_in[3];
  const float* b2 = (const float*)d_in[4];
  const float* qt = (const float*)d_in[5];
  const float* wq = (const float*)d_in[6];
  const float* bq = (const float*)d_in[7];
  const float* wk = (const float*)d_in[8];
  const float* wv = (const float*)d_in[10];
  const float* bv = (const float*)d_in[11];
  const float* wo = (const float*)d_in[12];
  const float* bo = (const float*)d_in[13];
  const float* wg = (const float*)d_in[14];
  float* out = (float*)d_out;

  char* ws = (char*)d_ws;
  size_t off = 0;
  auto alloc = [&](size_t bytes) {
    char* p = ws + off;
    off += (bytes + 255) & ~(size_t)255;
    return p;
  };
  const size_t XE = (size_t)NB * CB * DB;
  const size_t WE = (size_t)DB * DB;
  const size_t TE = (size_t)NB * QB * DB;

  bf16* x_bf   = (bf16*)alloc(XE * 2);
  bf16* V_bf   = (bf16*)alloc(XE * 2);
  bf16* wk_bf  = (bf16*)alloc(WE * 2);
  bf16* w1T    = (bf16*)alloc(WE * 2);
  bf16* w2T    = (bf16*)alloc(WE * 2);
  bf16* wvT    = (bf16*)alloc(WE * 2);
  bf16* wqT    = (bf16*)alloc(WE * 2);
  bf16* woT    = (bf16*)alloc(WE * 2);
  bf16* tokens = (bf16*)alloc(2 * TE * 2);
  bf16* h4     = (bf16*)alloc(2 * TE * 2);
  float* e01   = (float*)alloc(2 * TE * 4);
  bf16* ctx_bf = (bf16*)alloc(TE * 2);
  bf16* qt_bf  = (bf16*)alloc((size_t)QB * DB * 2);
  bf16* qproj  = (bf16*)alloc((size_t)QB * DB * 2);
  bf16* qk     = (bf16*)alloc((size_t)HB * QB * DB * 2);
  bf16* Sbuf   = (bf16*)alloc((size_t)NB * HB * QB * CB * 2);
  float* gates = (float*)alloc((size_t)NB * QB * 2 * 4);
  (void)ws_size; (void)in_sizes; (void)n_in; (void)out_size;

  // fused convert+pool, small converts, gating
  k_convpool<<<dim3(4, 64, 32), 256, 0, stream>>>(x, x_bf, tokens);
  k_convert<<<64, 256, 0, stream>>>(qt, (unsigned short*)qt_bf, (int)(QB * DB / 4));
  k_convert<<<1024, 256, 0, stream>>>(wk, (unsigned short*)wk_bf, (int)(WE / 4));
  k_gate<<<NB * QB / 4, 256, 0, stream>>>(tokens, wg, gates);

  // batched weight transposes
  TP5 tp;
  tp.s[0] = w1; tp.d[0] = w1T;
  tp.s[1] = w2; tp.d[1] = w2T;
  tp.s[2] = wv; tp.d[2] = wvT;
  tp.s[3] = wq; tp.d[3] = wqT;
  tp.s[4] = wo; tp.d[4] = woT;
  k_transpose5<<<dim3(64, 64, 5), dim3(32, 8), 0, stream>>>(tp);

  // q projection
  k_gemm<0><<<dim3(1, 16, 1), 256, 0, stream>>>(
      qt_bf, DB, 0, wqT, DB, 0, bq, qproj, DB, 0, QB, DB);

  // qk[h][q][d] = sum_dh qproj[q, h*128+dh] * wk[d, h*128+dh]
  k_gemm<0><<<dim3(1, 16, HB), 256, 0, stream>>>(
      qproj, DB, DHB, wk_bf, DB, DHB, nullptr, qk, DB, (long long)QB * DB, QB, DHB);

  // V projection (256^2)
  k_gemm256<0><<<dim3(512, 1, 1), 512, 0, stream>>>(
      x_bf, DB, 0, wvT, DB, 0, bv, V_bf, DB, 0, DB, 8);

  // scores: S[n] = qk @ x[n]^T (256^2, batched over n)
  k_gemm256<0><<<dim3(8, 1, NB), 512, 0, stream>>>(
      qk, DB, 0, x_bf, DB, (long long)CB * DB, nullptr,
      Sbuf, CB, (long long)HB * QB * CB, DB, 2);

  // cross attention (softmax + PV)
  k_attn<<<NB * HB, 256, 0, stream>>>(Sbuf, V_bf, ctx_bf);

  // output proj -> tokens rows 2048..4095
  k_gemm256<0><<<dim3(64, 1, 1), 512, 0, stream>>>(
      ctx_bf, DB, 0, woT, DB, 0, bo, tokens + (size_t)2048 * DB, DB, 0, DB, 8);

  // stacked expert MLP on [xs; res]
  k_gemm256<1><<<dim3(128, 1, 1), 512, 0, stream>>>(
      tokens, DB, 0, w1T, DB, 0, b1, h4, DB, 0, DB, 8);
  k_gemm256<2><<<dim3(128, 1, 1), 512, 0, stream>>>(
      h4, DB, 0, w2T, DB, 0, b2, e01, DB, 0, DB, 8);

  k_combine<<<4096, 256, 0, stream>>>(e01, gates, out);
}